// Round 16
// baseline (203.895 us; speedup 1.0000x reference)
//
#include <hip/hip_runtime.h>
#include <math.h>

// MS-SSIM loss, 5 levels, 11-tap separable Gaussian (sigma=1.5), VALID padding.
// Round 16: round-15 kernel body VERBATIM (verified, VGPR 84, DS-halved).
// Only the grids change: L0 was 768 blocks = 3 blocks/CU (37.5% wave cap,
// grid-limited). Halve strip heights -> 2x blocks at L0/L1 for stall coverage:
//   L0 rps 64->32 (1536 blocks, 6/CU), L1 rps 32->16 (768 blocks, 3/CU).
// Cost: +13.5% warmup iters/row at L0, +7% halo fetch — occupancy win dominates.
// 4-map transform (a=x+y, b=x-y -> P,Q,U,V), x2-rescaled emit algebra (exact).

struct GWin { float w[11]; };

__global__ __launch_bounds__(256)
void ssim_rows_kernel(const float* __restrict__ X, const float* __restrict__ Y,
                      float* __restrict__ poolX, float* __restrict__ poolY,
                      float* __restrict__ accum,   // [0..95]=ssim, [96..191]=cs
                      int S, int outS, int doPool, int rps, int tpcLog, GWin gw)
{
    __shared__ float4 ab[2][2][264];     // [slot][row01][col-pair unit {a,b,a,b}]

    const int tid = threadIdx.x;
    const int tpc = 1 << tpcLog;         // threads per channel = S/2
    const int lt  = tid & (tpc - 1);
    const int sub = tid >> tpcLog;
    const int ch  = blockIdx.z * (256 >> tpcLog) + sub;
    const int oy0 = blockIdx.x * rps;
    const int halfS = S >> 1;
    const int gc  = 2 * lt;              // thread's base input/output column

    int rowsOut = outS - oy0; if (rowsOut > rps) rowsOut = rps;
    const int NIT = (rowsOut + 11) >> 1; // iterations (2 input rows each)

    const float* Xc = X + (size_t)ch * S * S;
    const float* Yc = Y + (size_t)ch * S * S;

    float2 sx0, sy0, sx1, sy1;           // prefetched global data (2 rows)

    auto issue = [&](int baseRow) {
        int gr0 = baseRow;     if (gr0 > S - 1) gr0 = S - 1;
        int gr1 = baseRow + 1; if (gr1 > S - 1) gr1 = S - 1;
        sx0 = *reinterpret_cast<const float2*>(Xc + (size_t)gr0 * S + gc);
        sy0 = *reinterpret_cast<const float2*>(Yc + (size_t)gr0 * S + gc);
        sx1 = *reinterpret_cast<const float2*>(Xc + (size_t)gr1 * S + gc);
        sy1 = *reinterpret_cast<const float2*>(Yc + (size_t)gr1 * S + gc);
    };
    auto write_slot = [&](int sl) {      // one b128 per row: {a0,b0,a1,b1}
        ab[sl][0][tid] = make_float4(sx0.x + sy0.x, sx0.x - sy0.x,
                                     sx0.y + sy0.y, sx0.y - sy0.y);
        ab[sl][1][tid] = make_float4(sx1.x + sy1.x, sx1.x - sy1.x,
                                     sx1.y + sy1.y, sx1.y - sy1.y);
    };

    // pending v-conv partials: [col][slot], all static-indexed
    float pendP[2][12], pendQ[2][12], pendU[2][12], pendV[2][12];
    #pragma unroll
    for (int c = 0; c < 2; ++c)
        #pragma unroll
        for (int j = 0; j < 12; ++j) { pendP[c][j] = 0.f; pendQ[c][j] = 0.f; pendU[c][j] = 0.f; pendV[c][j] = 0.f; }

    float ssum = 0.f, csum = 0.f;
    const float C1x2 = 2e-4f, C2x2 = 1.8e-3f;
    const bool ok0 = (gc    ) < outS;
    const bool ok1 = (gc + 1) < outS;

    // prologue (zero the 8 overrun units read by the last threads)
    if (tid < 8) {
        float4 z = make_float4(0.f, 0.f, 0.f, 0.f);
        ab[0][0][256 + tid] = z; ab[0][1][256 + tid] = z;
        ab[1][0][256 + tid] = z; ab[1][1][256 + tid] = z;
    }
    issue(oy0);
    write_slot(0);
    issue(oy0 + 2);
    __syncthreads();

    for (int k = 0; k < NIT; ++k) {
        const int sl = k & 1;

        // ---- h-conv for both staged rows: 6 ds_read_b128 per row ----
        float hP[2][2], hQ[2][2], hU[2][2], hV[2][2];   // [row][col]
        float4 u0save[2];
        #pragma unroll
        for (int r = 0; r < 2; ++r) {
            const float4* bp = &ab[sl][r][tid];
            float4 u[6];
            #pragma unroll
            for (int i = 0; i < 6; ++i) u[i] = bp[i];
            u0save[r] = u[0];
            const float* v = reinterpret_cast<const float*>(u);  // v[2j]=a_j, v[2j+1]=b_j
            float sqa[12], sqb[12];
            #pragma unroll
            for (int j = 0; j < 12; ++j) {
                float a = v[2 * j], b = v[2 * j + 1];
                sqa[j] = a * a; sqb[j] = b * b;
            }
            float P0 = 0.f, Q0 = 0.f, U0 = 0.f, V0 = 0.f;
            float P1 = 0.f, Q1 = 0.f, U1 = 0.f, V1 = 0.f;
            #pragma unroll
            for (int t = 0; t < 11; ++t) {
                float wt = gw.w[t];
                P0 = fmaf(wt, v[2 * t],     P0);
                Q0 = fmaf(wt, v[2 * t + 1], Q0);
                U0 = fmaf(wt, sqa[t],       U0);
                V0 = fmaf(wt, sqb[t],       V0);
                P1 = fmaf(wt, v[2 * t + 2], P1);
                Q1 = fmaf(wt, v[2 * t + 3], Q1);
                U1 = fmaf(wt, sqa[t + 1],   U1);
                V1 = fmaf(wt, sqb[t + 1],   V1);
            }
            hP[r][0] = P0; hQ[r][0] = Q0; hU[r][0] = U0; hV[r][0] = V0;
            hP[r][1] = P1; hQ[r][1] = Q1; hU[r][1] = U1; hV[r][1] = V1;
        }

        // ---- v-accumulate into pending rings ----
        #pragma unroll
        for (int c = 0; c < 2; ++c) {
            #pragma unroll
            for (int j = 0; j <= 10; ++j) {          // row 2k: w[10-j] -> slot j
                float wt = gw.w[10 - j];
                pendP[c][j] = fmaf(wt, hP[0][c], pendP[c][j]);
                pendQ[c][j] = fmaf(wt, hQ[0][c], pendQ[c][j]);
                pendU[c][j] = fmaf(wt, hU[0][c], pendU[c][j]);
                pendV[c][j] = fmaf(wt, hV[0][c], pendV[c][j]);
            }
            #pragma unroll
            for (int j = 1; j <= 11; ++j) {          // row 2k+1: w[11-j] -> slot j
                float wt = gw.w[11 - j];
                pendP[c][j] = fmaf(wt, hP[1][c], pendP[c][j]);
                pendQ[c][j] = fmaf(wt, hQ[1][c], pendQ[c][j]);
                pendU[c][j] = fmaf(wt, hU[1][c], pendU[c][j]);
                pendV[c][j] = fmaf(wt, hV[1][c], pendV[c][j]);
            }
        }

        // ---- emit 2 finished output rows x 2 cols (x2-rescaled, exact) ----
        #pragma unroll
        for (int e = 0; e < 2; ++e) {
            int rel = 2 * k - 10 + e;
            bool rowok = (unsigned)rel < (unsigned)rowsOut;
            #pragma unroll
            for (int c = 0; c < 2; ++c) {
                float p = pendP[c][e], q = pendQ[c][e];
                float uu = pendU[c][e], vv = pendV[c][e];
                float p2 = p * p, q2 = q * q;
                float A = p2 - q2;                       // 2*(2 mu12)
                float csn = (uu - vv - A) + C2x2;        // 2*(2 sigma12) + 2C2
                float csd = (uu + vv - p2 - q2) + C2x2;
                float cs  = csn * __builtin_amdgcn_rcpf(csd);
                float ss  = (A + C1x2) * __builtin_amdgcn_rcpf(p2 + q2 + C1x2) * cs;
                if (rowok && (c ? ok1 : ok0)) { ssum += ss; csum += cs; }
            }
        }

        // ---- shift rings by 2 slots ----
        #pragma unroll
        for (int c = 0; c < 2; ++c) {
            #pragma unroll
            for (int j = 0; j < 10; ++j) {
                pendP[c][j] = pendP[c][j + 2]; pendQ[c][j] = pendQ[c][j + 2];
                pendU[c][j] = pendU[c][j + 2]; pendV[c][j] = pendV[c][j + 2];
            }
            pendP[c][10] = 0.f; pendP[c][11] = 0.f;
            pendQ[c][10] = 0.f; pendQ[c][11] = 0.f;
            pendU[c][10] = 0.f; pendU[c][11] = 0.f;
            pendV[c][10] = 0.f; pendV[c][11] = 0.f;
        }

        // ---- 2x2 pool from registers (thread's col pair = 1 pooled output) ----
        if (doPool && k < (rps >> 1)) {
            float sa = u0save[0].x + u0save[0].z + u0save[1].x + u0save[1].z;
            float sb = u0save[0].y + u0save[0].w + u0save[1].y + u0save[1].w;
            int prow = (oy0 >> 1) + k;
            size_t o = (size_t)ch * halfS * halfS + (size_t)prow * halfS + lt;
            poolX[o] = 0.125f * (sa + sb);
            poolY[o] = 0.125f * (sa - sb);
        }

        // ---- stage next rows (vmcnt drain lives here, after all compute) ----
        if (k + 1 < NIT) {
            write_slot(sl ^ 1);
            if (k + 2 < NIT) issue(oy0 + 2 * (k + 2));
        }
        __syncthreads();
    }

    // ---- per-channel-subgroup reduction + atomic accumulate ----
    {
        int rw = (tpc < 64) ? tpc : 64;
        for (int off = rw >> 1; off > 0; off >>= 1) {
            ssum += __shfl_down(ssum, off);
            csum += __shfl_down(csum, off);
        }
        if ((lt & 63) == 0) {
            atomicAdd(&accum[ch], ssum);
            atomicAdd(&accum[96 + ch], csum);
        }
    }
}

__global__ void finalize_kernel(const float* __restrict__ accum, float* __restrict__ out)
{
    __shared__ float red[2];
    const int t = threadIdx.x;   // 128 threads
    const float w[5]   = {0.0448f, 0.2856f, 0.3001f, 0.2363f, 0.1333f};
    const float inv[5] = {1.f / (502.f * 502.f), 1.f / (246.f * 246.f),
                          1.f / (118.f * 118.f), 1.f / (54.f * 54.f),
                          1.f / (22.f * 22.f)};
    float ms = 0.f;
    if (t < 96) {
        ms = 1.f;
        #pragma unroll
        for (int l = 0; l < 5; ++l) {
            float v = (l < 4) ? accum[l * 192 + 96 + t] : accum[l * 192 + t];
            v *= inv[l];
            v = fmaxf(v, 0.f);
            ms *= powf(v, w[l]);
        }
    }
    for (int off = 32; off > 0; off >>= 1) ms += __shfl_down(ms, off);
    int wid = t >> 6, lane = t & 63;
    if (lane == 0) red[wid] = ms;
    __syncthreads();
    if (t == 0) out[0] = 1.f - (red[0] + red[1]) * (1.f / 96.f);
}

extern "C" void kernel_launch(void* const* d_in, const int* in_sizes, int n_in,
                              void* d_out, int out_size, void* d_ws, size_t ws_size,
                              hipStream_t stream)
{
    (void)in_sizes; (void)n_in; (void)out_size; (void)ws_size;
    const float* X = (const float*)d_in[0];
    const float* Y = (const float*)d_in[1];
    float* out = (float*)d_out;
    float* ws  = (float*)d_ws;

    // Gaussian window (size 11, sigma 1.5), normalized
    GWin gw;
    {
        double g[11], s = 0.0;
        for (int i = 0; i < 11; ++i) { double d = i - 5; g[i] = exp(-(d * d) / 4.5); s += g[i]; }
        for (int i = 0; i < 11; ++i) gw.w[i] = (float)(g[i] / s);
    }

    // workspace layout (floats)
    float* accum = ws;                 // 5 levels * 192
    size_t off = 1024;
    float* p1x = ws + off; off += (size_t)96 * 256 * 256;
    float* p1y = ws + off; off += (size_t)96 * 256 * 256;
    float* p2x = ws + off; off += (size_t)96 * 128 * 128;
    float* p2y = ws + off; off += (size_t)96 * 128 * 128;
    float* p3x = ws + off; off += (size_t)96 * 64 * 64;
    float* p3y = ws + off; off += (size_t)96 * 64 * 64;
    float* p4x = ws + off; off += (size_t)96 * 32 * 32;
    float* p4y = ws + off; off += (size_t)96 * 32 * 32;

    hipMemsetAsync(accum, 0, 5 * 192 * sizeof(float), stream);

    auto launch = [&](const float* x, const float* y, float* px_, float* py_,
                      float* acc, int S, int outS, int pool, int rps, int tpcLog) {
        int nsub = 256 >> tpcLog;
        dim3 g((outS + rps - 1) / rps, 1, 96 / nsub);
        ssim_rows_kernel<<<g, 256, 0, stream>>>(x, y, px_, py_, acc, S, outS, pool,
                                                rps, tpcLog, gw);
    };

    // pool coverage per level: strips * rps/2 == halfS; tail strips NIT >= rps/2
    launch(X,   Y,   p1x, p1y, accum + 0,   512, 502, 1, 32, 8);  // 16 strips x 96  = 1536 blocks
    launch(p1x, p1y, p2x, p2y, accum + 192, 256, 246, 1, 16, 7);  // 16 x 48        = 768
    launch(p2x, p2y, p3x, p3y, accum + 384, 128, 118, 1, 16, 6);  // 8 x 24         = 192
    launch(p3x, p3y, p4x, p4y, accum + 576, 64,  54,  1, 16, 5);  // 4 x 12         = 48
    launch(p4x, p4y, nullptr, nullptr, accum + 768, 32, 22, 0, 22, 4);  // 1 x 6

    finalize_kernel<<<1, 128, 0, stream>>>(accum, out);
}

// Round 17
// 187.193 us; speedup vs baseline: 1.0892x; 1.0892x over previous
//
#include <hip/hip_runtime.h>
#include <math.h>

// MS-SSIM loss, 5 levels, 11-tap separable Gaussian (sigma=1.5), VALID padding.
// Round 17: round-15 body/grids VERBATIM except the conv math is packed-f32:
// LDS units {a,b,a,b} make {a_j,b_j} adjacent VGPR pairs, so {P,Q} and {U,V}
// chains become v_pk_fma_f32 (VOP3P): h-conv 12 pk_mul + 44 pk_fma per row,
// v-accum 88 pk_fma, ring shift 40 b64 movs — ~40% fewer VALU instructions.
// (r12 tried pk when DS was the wall and it was wasted; r15 halved DS, VALU is
// now the binding pipe at 61% busy — this time the cut lands on the bottleneck.)
// 4-map transform (a=x+y, b=x-y -> P,Q,U,V), x2-rescaled emit algebra (exact).

typedef float f32x2 __attribute__((ext_vector_type(2)));

struct GWin { float w[11]; };

__global__ __launch_bounds__(256)
void ssim_rows_kernel(const float* __restrict__ X, const float* __restrict__ Y,
                      float* __restrict__ poolX, float* __restrict__ poolY,
                      float* __restrict__ accum,   // [0..95]=ssim, [96..191]=cs
                      int S, int outS, int doPool, int rps, int tpcLog, GWin gw)
{
    __shared__ float4 ab[2][2][264];     // [slot][row01][col-pair unit {a,b,a,b}]

    const int tid = threadIdx.x;
    const int tpc = 1 << tpcLog;         // threads per channel = S/2
    const int lt  = tid & (tpc - 1);
    const int sub = tid >> tpcLog;
    const int ch  = blockIdx.z * (256 >> tpcLog) + sub;
    const int oy0 = blockIdx.x * rps;
    const int halfS = S >> 1;
    const int gc  = 2 * lt;              // thread's base input/output column

    int rowsOut = outS - oy0; if (rowsOut > rps) rowsOut = rps;
    const int NIT = (rowsOut + 11) >> 1; // iterations (2 input rows each)

    const float* Xc = X + (size_t)ch * S * S;
    const float* Yc = Y + (size_t)ch * S * S;

    float2 sx0, sy0, sx1, sy1;           // prefetched global data (2 rows)

    auto issue = [&](int baseRow) {
        int gr0 = baseRow;     if (gr0 > S - 1) gr0 = S - 1;
        int gr1 = baseRow + 1; if (gr1 > S - 1) gr1 = S - 1;
        sx0 = *reinterpret_cast<const float2*>(Xc + (size_t)gr0 * S + gc);
        sy0 = *reinterpret_cast<const float2*>(Yc + (size_t)gr0 * S + gc);
        sx1 = *reinterpret_cast<const float2*>(Xc + (size_t)gr1 * S + gc);
        sy1 = *reinterpret_cast<const float2*>(Yc + (size_t)gr1 * S + gc);
    };
    auto write_slot = [&](int sl) {      // one b128 per row: {a0,b0,a1,b1}
        ab[sl][0][tid] = make_float4(sx0.x + sy0.x, sx0.x - sy0.x,
                                     sx0.y + sy0.y, sx0.y - sy0.y);
        ab[sl][1][tid] = make_float4(sx1.x + sy1.x, sx1.x - sy1.x,
                                     sx1.y + sy1.y, sx1.y - sy1.y);
    };

    // pending v-conv partials: [col][slot], packed {P,Q} / {U,V}, static-indexed
    f32x2 pendPQ[2][12], pendUV[2][12];
    #pragma unroll
    for (int c = 0; c < 2; ++c)
        #pragma unroll
        for (int j = 0; j < 12; ++j) { pendPQ[c][j] = (f32x2){0.f, 0.f}; pendUV[c][j] = (f32x2){0.f, 0.f}; }

    float ssum = 0.f, csum = 0.f;
    const float C1x2 = 2e-4f, C2x2 = 1.8e-3f;
    const bool ok0 = (gc    ) < outS;
    const bool ok1 = (gc + 1) < outS;

    // prologue (zero the 8 overrun units read by the last threads)
    if (tid < 8) {
        float4 z = make_float4(0.f, 0.f, 0.f, 0.f);
        ab[0][0][256 + tid] = z; ab[0][1][256 + tid] = z;
        ab[1][0][256 + tid] = z; ab[1][1][256 + tid] = z;
    }
    issue(oy0);
    write_slot(0);
    issue(oy0 + 2);
    __syncthreads();

    for (int k = 0; k < NIT; ++k) {
        const int sl = k & 1;

        // ---- h-conv for both staged rows: 6 ds_read_b128 per row, packed math ----
        f32x2 hPQ[2][2], hUV[2][2];      // [row][col] = {P,Q} / {U,V}
        f32x2 keep0[2], keep1[2];        // vv[0], vv[1] per row (for pool)
        #pragma unroll
        for (int r = 0; r < 2; ++r) {
            const float4* bp = &ab[sl][r][tid];
            float4 u[6];
            #pragma unroll
            for (int i = 0; i < 6; ++i) u[i] = bp[i];
            const f32x2* vv = reinterpret_cast<const f32x2*>(u);   // vv[j] = {a_j, b_j}
            keep0[r] = vv[0]; keep1[r] = vv[1];
            f32x2 sq[12];
            #pragma unroll
            for (int j = 0; j < 12; ++j) sq[j] = vv[j] * vv[j];    // pk_mul
            f32x2 pq0 = {0.f, 0.f}, uv0 = {0.f, 0.f};
            f32x2 pq1 = {0.f, 0.f}, uv1 = {0.f, 0.f};
            #pragma unroll
            for (int t = 0; t < 11; ++t) {
                float wt = gw.w[t];
                f32x2 ws = {wt, wt};
                pq0 = __builtin_elementwise_fma(ws, vv[t],     pq0);
                uv0 = __builtin_elementwise_fma(ws, sq[t],     uv0);
                pq1 = __builtin_elementwise_fma(ws, vv[t + 1], pq1);
                uv1 = __builtin_elementwise_fma(ws, sq[t + 1], uv1);
            }
            hPQ[r][0] = pq0; hUV[r][0] = uv0;
            hPQ[r][1] = pq1; hUV[r][1] = uv1;
        }

        // ---- v-accumulate into pending rings (packed) ----
        #pragma unroll
        for (int c = 0; c < 2; ++c) {
            #pragma unroll
            for (int j = 0; j <= 10; ++j) {          // row 2k: w[10-j] -> slot j
                float wt = gw.w[10 - j];
                f32x2 ws = {wt, wt};
                pendPQ[c][j] = __builtin_elementwise_fma(ws, hPQ[0][c], pendPQ[c][j]);
                pendUV[c][j] = __builtin_elementwise_fma(ws, hUV[0][c], pendUV[c][j]);
            }
            #pragma unroll
            for (int j = 1; j <= 11; ++j) {          // row 2k+1: w[11-j] -> slot j
                float wt = gw.w[11 - j];
                f32x2 ws = {wt, wt};
                pendPQ[c][j] = __builtin_elementwise_fma(ws, hPQ[1][c], pendPQ[c][j]);
                pendUV[c][j] = __builtin_elementwise_fma(ws, hUV[1][c], pendUV[c][j]);
            }
        }

        // ---- emit 2 finished output rows x 2 cols (x2-rescaled, exact) ----
        #pragma unroll
        for (int e = 0; e < 2; ++e) {
            int rel = 2 * k - 10 + e;
            bool rowok = (unsigned)rel < (unsigned)rowsOut;
            #pragma unroll
            for (int c = 0; c < 2; ++c) {
                float p = pendPQ[c][e].x, q = pendPQ[c][e].y;
                float uu = pendUV[c][e].x, vv_ = pendUV[c][e].y;
                float p2 = p * p, q2 = q * q;
                float A = p2 - q2;                       // 2*(2 mu12)
                float csn = (uu - vv_ - A) + C2x2;       // 2*(2 sigma12) + 2C2
                float csd = (uu + vv_ - p2 - q2) + C2x2;
                float cs  = csn * __builtin_amdgcn_rcpf(csd);
                float ss  = (A + C1x2) * __builtin_amdgcn_rcpf(p2 + q2 + C1x2) * cs;
                if (rowok && (c ? ok1 : ok0)) { ssum += ss; csum += cs; }
            }
        }

        // ---- shift rings by 2 slots (b64 moves) ----
        #pragma unroll
        for (int c = 0; c < 2; ++c) {
            #pragma unroll
            for (int j = 0; j < 10; ++j) {
                pendPQ[c][j] = pendPQ[c][j + 2];
                pendUV[c][j] = pendUV[c][j + 2];
            }
            pendPQ[c][10] = (f32x2){0.f, 0.f}; pendPQ[c][11] = (f32x2){0.f, 0.f};
            pendUV[c][10] = (f32x2){0.f, 0.f}; pendUV[c][11] = (f32x2){0.f, 0.f};
        }

        // ---- 2x2 pool from registers (thread's col pair = 1 pooled output) ----
        if (doPool && k < (rps >> 1)) {
            float sa = keep0[0].x + keep1[0].x + keep0[1].x + keep1[1].x;
            float sb = keep0[0].y + keep1[0].y + keep0[1].y + keep1[1].y;
            int prow = (oy0 >> 1) + k;
            size_t o = (size_t)ch * halfS * halfS + (size_t)prow * halfS + lt;
            poolX[o] = 0.125f * (sa + sb);
            poolY[o] = 0.125f * (sa - sb);
        }

        // ---- stage next rows (vmcnt drain lives here, after all compute) ----
        if (k + 1 < NIT) {
            write_slot(sl ^ 1);
            if (k + 2 < NIT) issue(oy0 + 2 * (k + 2));
        }
        __syncthreads();
    }

    // ---- per-channel-subgroup reduction + atomic accumulate ----
    {
        int rw = (tpc < 64) ? tpc : 64;
        for (int off = rw >> 1; off > 0; off >>= 1) {
            ssum += __shfl_down(ssum, off);
            csum += __shfl_down(csum, off);
        }
        if ((lt & 63) == 0) {
            atomicAdd(&accum[ch], ssum);
            atomicAdd(&accum[96 + ch], csum);
        }
    }
}

__global__ void finalize_kernel(const float* __restrict__ accum, float* __restrict__ out)
{
    __shared__ float red[2];
    const int t = threadIdx.x;   // 128 threads
    const float w[5]   = {0.0448f, 0.2856f, 0.3001f, 0.2363f, 0.1333f};
    const float inv[5] = {1.f / (502.f * 502.f), 1.f / (246.f * 246.f),
                          1.f / (118.f * 118.f), 1.f / (54.f * 54.f),
                          1.f / (22.f * 22.f)};
    float ms = 0.f;
    if (t < 96) {
        ms = 1.f;
        #pragma unroll
        for (int l = 0; l < 5; ++l) {
            float v = (l < 4) ? accum[l * 192 + 96 + t] : accum[l * 192 + t];
            v *= inv[l];
            v = fmaxf(v, 0.f);
            ms *= powf(v, w[l]);
        }
    }
    for (int off = 32; off > 0; off >>= 1) ms += __shfl_down(ms, off);
    int wid = t >> 6, lane = t & 63;
    if (lane == 0) red[wid] = ms;
    __syncthreads();
    if (t == 0) out[0] = 1.f - (red[0] + red[1]) * (1.f / 96.f);
}

extern "C" void kernel_launch(void* const* d_in, const int* in_sizes, int n_in,
                              void* d_out, int out_size, void* d_ws, size_t ws_size,
                              hipStream_t stream)
{
    (void)in_sizes; (void)n_in; (void)out_size; (void)ws_size;
    const float* X = (const float*)d_in[0];
    const float* Y = (const float*)d_in[1];
    float* out = (float*)d_out;
    float* ws  = (float*)d_ws;

    // Gaussian window (size 11, sigma 1.5), normalized
    GWin gw;
    {
        double g[11], s = 0.0;
        for (int i = 0; i < 11; ++i) { double d = i - 5; g[i] = exp(-(d * d) / 4.5); s += g[i]; }
        for (int i = 0; i < 11; ++i) gw.w[i] = (float)(g[i] / s);
    }

    // workspace layout (floats)
    float* accum = ws;                 // 5 levels * 192
    size_t off = 1024;
    float* p1x = ws + off; off += (size_t)96 * 256 * 256;
    float* p1y = ws + off; off += (size_t)96 * 256 * 256;
    float* p2x = ws + off; off += (size_t)96 * 128 * 128;
    float* p2y = ws + off; off += (size_t)96 * 128 * 128;
    float* p3x = ws + off; off += (size_t)96 * 64 * 64;
    float* p3y = ws + off; off += (size_t)96 * 64 * 64;
    float* p4x = ws + off; off += (size_t)96 * 32 * 32;
    float* p4y = ws + off; off += (size_t)96 * 32 * 32;

    hipMemsetAsync(accum, 0, 5 * 192 * sizeof(float), stream);

    auto launch = [&](const float* x, const float* y, float* px_, float* py_,
                      float* acc, int S, int outS, int pool, int rps, int tpcLog) {
        int nsub = 256 >> tpcLog;
        dim3 g((outS + rps - 1) / rps, 1, 96 / nsub);
        ssim_rows_kernel<<<g, 256, 0, stream>>>(x, y, px_, py_, acc, S, outS, pool,
                                                rps, tpcLog, gw);
    };

    // r15 grids exactly (best measured): tpc = S/2 threads per channel
    launch(X,   Y,   p1x, p1y, accum + 0,   512, 502, 1, 64, 8);  // 8 strips x 96
    launch(p1x, p1y, p2x, p2y, accum + 192, 256, 246, 1, 32, 7);  // 8 x 48
    launch(p2x, p2y, p3x, p3y, accum + 384, 128, 118, 1, 16, 6);  // 8 x 24
    launch(p3x, p3y, p4x, p4y, accum + 576, 64,  54,  1, 16, 5);  // 4 x 12
    launch(p4x, p4y, nullptr, nullptr, accum + 768, 32, 22, 0, 22, 4);  // 1 x 6

    finalize_kernel<<<1, 128, 0, stream>>>(accum, out);
}